// Round 13
// baseline (205.262 us; speedup 1.0000x reference)
//
#include <hip/hip_runtime.h>

#define B_ROWS 4096
#define K_Q    32768
#define D_DIM  256
#define C_CLS  100

typedef unsigned char u8;
typedef __attribute__((ext_vector_type(4))) int i32x4;
typedef __attribute__((ext_vector_type(8))) int i32x8;
typedef __attribute__((ext_vector_type(16))) float f32x16;

__device__ inline float fast_sqrt(float x) { return __builtin_amdgcn_sqrtf(x); }

__device__ inline i32x8 mk8(i32x4 lo, i32x4 hi) {
  return __builtin_shufflevector(lo, hi, 0, 1, 2, 3, 4, 5, 6, 7);
}

#define GLDS16(g, l) __builtin_amdgcn_global_load_lds( \
    (const __attribute__((address_space(1))) unsigned int*)(g), \
    (__attribute__((address_space(3))) unsigned int*)(l), 16, 0, 0)

// fp8 storage: PLAIN k-major 256B/row (the 32x32x64 MFMA fragment is 32
// contiguous k-bytes per lane -- no frag-major needed).

// ---------- K1: per-class partial sums + fused fp8 cast of Q + zero S ----------
__global__ __launch_bounds__(512) void k_hist(
    const float* __restrict__ q, const int* __restrict__ lab,
    float* __restrict__ partial, u8* __restrict__ qf8,
    float* __restrict__ S_all, float* __restrict__ S_match) {
  __shared__ float lsum[C_CLS * 64];    // 25.6 KB
  const int kc = blockIdx.x, dc = blockIdx.y;
  const int tid = threadIdx.x, w = tid >> 6, l = tid & 63;
  if (dc == 0 && tid < 64) {            // replaces the memset node
    S_all[kc * 64 + tid] = 0.f;
    S_match[kc * 64 + tid] = 0.f;
  }
  for (int i = tid; i < C_CLS * 64; i += 512) lsum[i] = 0.f;
  __syncthreads();
  const int col = dc * 64 + l;
  const int k0 = kc * 512 + w * 64;
  #pragma unroll 4
  for (int r = 0; r < 64; ++r) {
    const int k = k0 + r;
    const int c = lab[k];                         // wave-uniform
    float v = q[(size_t)k * D_DIM + col];
    atomicAdd(&lsum[c * 64 + l], v);              // ds_add_f32
    int p8 = __builtin_amdgcn_cvt_pk_fp8_f32(v * 16.f, v * 16.f, 0, false);
    qf8[(size_t)k * D_DIM + col] = (u8)p8;        // plain layout, 64B/wave coalesced
  }
  __syncthreads();
  float* pb = partial + (size_t)(kc * 4 + dc) * (C_CLS * 64);
  for (int i = tid; i < C_CLS * 64; i += 512) pb[i] = lsum[i];
}

// ---------- K2: counts (from lab) + partial-reduce + centroid normalize ----------
__global__ __launch_bounds__(256) void k_cnorm(
    const int* __restrict__ lab, const float* __restrict__ partial,
    int* __restrict__ counts, float* __restrict__ cnorm) {
  __shared__ float red[4];
  __shared__ int credi[4];
  const int c = blockIdx.x, d = threadIdx.x;
  int cnt = 0;
  #pragma unroll 8
  for (int i = 0; i < K_Q / 256; ++i) cnt += (lab[d + i * 256] == c) ? 1 : 0;
  #pragma unroll
  for (int o = 1; o < 64; o <<= 1) cnt += __shfl_xor(cnt, o);
  if ((d & 63) == 0) credi[d >> 6] = cnt;
  float s = 0.f;
  const int dcsel = d >> 6, low = d & 63;
  for (int kc = 0; kc < 64; ++kc)
    s += partial[(size_t)(kc * 4 + dcsel) * (C_CLS * 64) + c * 64 + low];
  __syncthreads();
  const int cnt_all = credi[0] + credi[1] + credi[2] + credi[3];
  float v = s / (float)cnt_all;
  float ss = v * v;
  #pragma unroll
  for (int o = 1; o < 64; o <<= 1) ss += __shfl_xor(ss, o);
  if ((d & 63) == 0) red[d >> 6] = ss;
  __syncthreads();
  float norm = sqrtf(red[0] + red[1] + red[2] + red[3]);
  cnorm[c * D_DIM + d] = v / fmaxf(norm, 1e-12f);
  if (d == 0) counts[c] = cnt_all;
}

// ---------- K3: pseudo-labels (fp32 argmax, class-pair ILP) + plain fp8 A cast ----------
__global__ void k_pseudo(const float* __restrict__ bf, const float* __restrict__ cn,
                         int* __restrict__ pseudo, u8* __restrict__ af8) {
  const int tid = threadIdx.x;
  const int rloc = tid >> 4, sub = tid & 15;
  const int row = blockIdx.x * 16 + rloc;
  float4 a[4];
  const float4* ap = (const float4*)(bf + (size_t)row * D_DIM);
  #pragma unroll
  for (int j = 0; j < 4; ++j) a[j] = ap[sub + j * 16];
  #pragma unroll
  for (int j = 0; j < 4; ++j) {
    int lo = __builtin_amdgcn_cvt_pk_fp8_f32(a[j].x * 16.f, a[j].y * 16.f, 0, false);
    int pk = __builtin_amdgcn_cvt_pk_fp8_f32(a[j].z * 16.f, a[j].w * 16.f, lo, true);
    *(unsigned int*)(af8 + (size_t)row * D_DIM + (sub + j * 16) * 4) = (unsigned int)pk;
  }
  float best = -1e30f; int bi = 0;
  for (int c = 0; c < C_CLS; c += 2) {
    const float4* cp0 = (const float4*)(cn + c * D_DIM);
    const float4* cp1 = (const float4*)(cn + (c + 1) * D_DIM);
    float s0 = 0.f, s1 = 0.f;
    #pragma unroll
    for (int j = 0; j < 4; ++j) {
      float4 b0 = cp0[sub + j * 16];
      float4 b1 = cp1[sub + j * 16];
      s0 += a[j].x * b0.x + a[j].y * b0.y + a[j].z * b0.z + a[j].w * b0.w;
      s1 += a[j].x * b1.x + a[j].y * b1.y + a[j].z * b1.z + a[j].w * b1.w;
    }
    s0 += __shfl_xor(s0, 1); s1 += __shfl_xor(s1, 1);
    s0 += __shfl_xor(s0, 2); s1 += __shfl_xor(s1, 2);
    s0 += __shfl_xor(s0, 4); s1 += __shfl_xor(s1, 4);
    s0 += __shfl_xor(s0, 8); s1 += __shfl_xor(s1, 8);
    if (s0 > best) { best = s0; bi = c; }
    if (s1 > best) { best = s1; bi = c + 1; }
  }
  if (sub == 0) pseudo[row] = bi;
}

// ---------- K5: MX-scaled fp8 MFMA GEMM (32x32x64, scales=1.0) + sqrt + masked sums ----------
// 512 blocks x 512 thr (8 waves row-stacked, 32 rows each). 16 phases of 64 cols;
// wave = 32 rows x 64 cols (2 n-tiles of 32), 4 k-steps of 64. A: 32B/lane
// contiguous. B via LDS, XOR-swizzle (row&15)<<4 both sides. 2.25x the
// non-scaled fp8 MFMA rate (4686 vs 2075 TF) -> MFMA floor ~14us (was 33).
__global__ __launch_bounds__(512, 4) void k_main(
    const u8* __restrict__ Af8, const u8* __restrict__ Qf8,
    const int* __restrict__ lab, const int* __restrict__ pseudo,
    float* __restrict__ S_all, float* __restrict__ S_match) {
  __shared__ u8 Bs[2][64 * 256];        // 2 x 16KB

  const int bid = blockIdx.x;
  const int xcd = bid & 7, idx = bid >> 3;
  const int cs = xcd * 4 + (idx >> 4);            // 0..31 col slice (1024 cols)
  const int rb = idx & 15;                        // 0..15 row block (256 rows)

  const int tid = threadIdx.x;
  const int w = tid >> 6, l = tid & 63;
  const int c32 = l & 31, hi32 = l >> 5;
  const int rowA = rb * 256 + w * 32;             // wave's 32 rows
  const int colbase = cs * 1024;

  // A-fragments: lane holds row rowA+c32, k = ks*64 + hi32*32 + [0,32). 32 regs.
  i32x4 areg[4][2];
  {
    const u8* ap = Af8 + (size_t)(rowA + c32) * D_DIM + hi32 * 32;
    #pragma unroll
    for (int ks = 0; ks < 4; ++ks) {
      areg[ks][0] = *(const i32x4*)(ap + ks * 64);
      areg[ks][1] = *(const i32x4*)(ap + ks * 64 + 16);
    }
  }

  // pseudo-labels, byte-packed: psepk[g] = rows rowA + 4*hi32 + 8*g + {0..3}
  int psepk[4];
  #pragma unroll
  for (int g = 0; g < 4; ++g) {
    const int* pp = pseudo + rowA + hi32 * 4 + g * 8;
    psepk[g] = pp[0] | (pp[1] << 8) | (pp[2] << 16) | (pp[3] << 24);
  }

  float pa[16], pm[16];
  #pragma unroll
  for (int r = 0; r < 16; ++r) { pa[r] = 0.f; pm[r] = 0.f; }

  // Staging: linear LDS dest (tid*16 + i*8192); source pre-swizzled with the
  // read involution: row = i*32 + (t>>4), slot = (t&15)<<4 ^ ((row&15)<<4).
  const int strow = tid >> 4;                     // 0..31
  const int sinner = (((tid & 15) ^ (strow & 15)) << 4);
  const u8* sbase = Qf8 + (size_t)(colbase + strow) * D_DIM + sinner;

#define STAGE(buf, ph)                                                    \
  { const u8* s_ = sbase + (size_t)(ph) * (64 * D_DIM);                   \
    GLDS16(s_,              (buf) + tid * 16);                            \
    GLDS16(s_ + 32 * D_DIM, (buf) + 8192 + tid * 16); }

  const int* lptr = lab + colbase + c32;
  const int xorm = (c32 & 15) << 4;               // read-side swizzle (row = n*32+c32)
  const unsigned int SC1 = 0x7F7F7F7Fu;           // E8M0 = 2^0 per 32-elem block

  STAGE(&Bs[0][0], 0);                            // prologue

  #pragma unroll 1
  for (int ph = 0; ph < 16; ++ph) {
    __syncthreads();                              // buf[ph&1] staged
    if (ph + 1 < 16) STAGE(&Bs[(ph + 1) & 1][0], ph + 1);
    const u8* bs = &Bs[ph & 1][0];
    const int lbl0 = lptr[ph * 64];
    const int lbl1 = lptr[ph * 64 + 32];

    f32x16 acc0{}, acc1{};
    #pragma unroll
    for (int ks = 0; ks < 4; ++ks) {
      const int off = ks * 64 + hi32 * 32;
      i32x4 b0l = *(const i32x4*)(bs + c32 * 256 + (off ^ xorm));
      i32x4 b0h = *(const i32x4*)(bs + c32 * 256 + ((off + 16) ^ xorm));
      i32x4 b1l = *(const i32x4*)(bs + (32 + c32) * 256 + (off ^ xorm));
      i32x4 b1h = *(const i32x4*)(bs + (32 + c32) * 256 + ((off + 16) ^ xorm));
      i32x8 av = mk8(areg[ks][0], areg[ks][1]);
      acc0 = __builtin_amdgcn_mfma_scale_f32_32x32x64_f8f6f4(
          av, mk8(b0l, b0h), acc0, 0, 0, 0, SC1, 0, SC1);
      acc1 = __builtin_amdgcn_mfma_scale_f32_32x32x64_f8f6f4(
          av, mk8(b1l, b1h), acc1, 0, 0, 0, SC1, 0, SC1);
    }

    // MAE epilogue: sim = acc/256 -> mae = sqrt(2 - acc/128 + 1e-6)
    #pragma unroll
    for (int r = 0; r < 16; ++r) {
      const int p = (psepk[r >> 2] >> ((r & 3) * 8)) & 255;
      float mae0 = fast_sqrt(fmaxf(__builtin_fmaf(-0.0078125f, acc0[r], 2.000001f), 0.0f));
      float mae1 = fast_sqrt(fmaxf(__builtin_fmaf(-0.0078125f, acc1[r], 2.000001f), 0.0f));
      pa[r] += mae0 + mae1;
      pm[r] += (lbl0 == p ? mae0 : 0.0f) + (lbl1 == p ? mae1 : 0.0f);
    }
  }

  // once per block: reduce over the 32 col-lanes, then atomics
  #pragma unroll
  for (int r = 0; r < 16; ++r) {
    float va = pa[r], vm = pm[r];
    va += __shfl_xor(va, 1); vm += __shfl_xor(vm, 1);
    va += __shfl_xor(va, 2); vm += __shfl_xor(vm, 2);
    va += __shfl_xor(va, 4); vm += __shfl_xor(vm, 4);
    va += __shfl_xor(va, 8); vm += __shfl_xor(vm, 8);
    va += __shfl_xor(va, 16); vm += __shfl_xor(vm, 16);
    if (c32 == 0) {
      const int gr = rowA + (r & 3) + 8 * (r >> 2) + 4 * hi32;
      atomicAdd(&S_all[gr], va);
      atomicAdd(&S_match[gr], vm);
    }
  }
#undef STAGE
}

// ---------- K6: final scalar ----------
__global__ void k_final(const float* __restrict__ S_all, const float* __restrict__ S_match,
                        const int* __restrict__ pseudo, const int* __restrict__ counts,
                        float* __restrict__ out) {
  __shared__ float r1[16], r2[16];
  const int tid = threadIdx.x;
  float s1 = 0.f, s2 = 0.f;
  for (int b = tid; b < B_ROWS; b += 1024) {
    float cnt = (float)counts[pseudo[b]];
    float sm = S_match[b], sa = S_all[b];
    s1 += sm / (cnt + 1e-6f);
    s2 += (sa - sm) / ((float)K_Q - cnt + 1e-6f);
  }
  #pragma unroll
  for (int o = 1; o < 64; o <<= 1) { s1 += __shfl_xor(s1, o); s2 += __shfl_xor(s2, o); }
  if ((tid & 63) == 0) { r1[tid >> 6] = s1; r2[tid >> 6] = s2; }
  __syncthreads();
  if (tid == 0) {
    float t1 = 0.f, t2 = 0.f;
    #pragma unroll
    for (int i = 0; i < 16; ++i) { t1 += r1[i]; t2 += r2[i]; }
    out[0] = t1 / (float)B_ROWS + 2.0f - t2 / (float)B_ROWS;
  }
}

extern "C" void kernel_launch(void* const* d_in, const int* in_sizes, int n_in,
                              void* d_out, int out_size, void* d_ws, size_t ws_size,
                              hipStream_t stream) {
  const float* batch = (const float*)d_in[0];
  const float* queue = (const float*)d_in[1];
  const int*   lab   = (const int*)d_in[2];

  char* ws = (char*)d_ws;
  float* S_all   = (float*)(ws + 0);             // 16KB (zeroed by k_hist)
  float* S_match = (float*)(ws + 16384);         // 16KB (zeroed by k_hist)
  int*   counts  = (int*)  (ws + 32768);         // 512B
  float* cnorm   = (float*)(ws + 33280);         // 100KB
  int*   pseudo  = (int*)  (ws + 135680);        // 16KB
  u8*    Af8     = (u8*)   (ws + 152064);        // 1MB
  u8*    Qf8     = (u8*)   (ws + 1200640);       // 8MB
  float* partial = (float*)(ws + 9589248);       // 6.5MB

  k_hist  <<<dim3(64, 4), 512, 0, stream>>>(queue, lab, partial, Qf8, S_all, S_match);
  k_cnorm <<<C_CLS, 256, 0, stream>>>(lab, partial, counts, cnorm);
  k_pseudo<<<B_ROWS / 16, 256, 0, stream>>>(batch, cnorm, pseudo, Af8);
  k_main  <<<512, 512, 0, stream>>>(Af8, Qf8, lab, pseudo, S_all, S_match);
  k_final <<<1, 1024, 0, stream>>>(S_all, S_match, pseudo, counts, (float*)d_out);
}

// Round 14
// 155.402 us; speedup vs baseline: 1.3208x; 1.3208x over previous
//
#include <hip/hip_runtime.h>

#define B_ROWS 4096
#define K_Q    32768
#define D_DIM  256
#define C_CLS  100

typedef unsigned char u8;
typedef __attribute__((ext_vector_type(4))) int i32x4;
typedef __attribute__((ext_vector_type(8))) int i32x8;
typedef __attribute__((ext_vector_type(16))) float f32x16;

__device__ inline float fast_sqrt(float x) { return __builtin_amdgcn_sqrtf(x); }

__device__ inline i32x8 mk8(i32x4 lo, i32x4 hi) {
  return __builtin_shufflevector(lo, hi, 0, 1, 2, 3, 4, 5, 6, 7);
}

#define GLDS16(g, l) __builtin_amdgcn_global_load_lds( \
    (const __attribute__((address_space(1))) unsigned int*)(g), \
    (__attribute__((address_space(3))) unsigned int*)(l), 16, 0, 0)

// fp8 storage: PLAIN k-major 256B/row (the 32x32x64 MFMA fragment is 32
// contiguous k-bytes per lane).

// ---------- K1: per-class partial sums + fused fp8 cast of Q + zero S ----------
__global__ __launch_bounds__(512) void k_hist(
    const float* __restrict__ q, const int* __restrict__ lab,
    float* __restrict__ partial, u8* __restrict__ qf8,
    float* __restrict__ S_all, float* __restrict__ S_match) {
  __shared__ float lsum[C_CLS * 64];    // 25.6 KB
  const int kc = blockIdx.x, dc = blockIdx.y;
  const int tid = threadIdx.x, w = tid >> 6, l = tid & 63;
  if (dc == 0 && tid < 64) {            // replaces the memset node
    S_all[kc * 64 + tid] = 0.f;
    S_match[kc * 64 + tid] = 0.f;
  }
  for (int i = tid; i < C_CLS * 64; i += 512) lsum[i] = 0.f;
  __syncthreads();
  const int col = dc * 64 + l;
  const int k0 = kc * 512 + w * 64;
  #pragma unroll 4
  for (int r = 0; r < 64; ++r) {
    const int k = k0 + r;
    const int c = lab[k];                         // wave-uniform
    float v = q[(size_t)k * D_DIM + col];
    atomicAdd(&lsum[c * 64 + l], v);              // ds_add_f32
    int p8 = __builtin_amdgcn_cvt_pk_fp8_f32(v * 16.f, v * 16.f, 0, false);
    qf8[(size_t)k * D_DIM + col] = (u8)p8;        // plain layout, 64B/wave coalesced
  }
  __syncthreads();
  float* pb = partial + (size_t)(kc * 4 + dc) * (C_CLS * 64);
  for (int i = tid; i < C_CLS * 64; i += 512) pb[i] = lsum[i];
}

// ---------- K2: counts (from lab) + partial-reduce + centroid normalize ----------
__global__ __launch_bounds__(256) void k_cnorm(
    const int* __restrict__ lab, const float* __restrict__ partial,
    int* __restrict__ counts, float* __restrict__ cnorm) {
  __shared__ float red[4];
  __shared__ int credi[4];
  const int c = blockIdx.x, d = threadIdx.x;
  int cnt = 0;
  #pragma unroll 8
  for (int i = 0; i < K_Q / 256; ++i) cnt += (lab[d + i * 256] == c) ? 1 : 0;
  #pragma unroll
  for (int o = 1; o < 64; o <<= 1) cnt += __shfl_xor(cnt, o);
  if ((d & 63) == 0) credi[d >> 6] = cnt;
  float s = 0.f;
  const int dcsel = d >> 6, low = d & 63;
  for (int kc = 0; kc < 64; ++kc)
    s += partial[(size_t)(kc * 4 + dcsel) * (C_CLS * 64) + c * 64 + low];
  __syncthreads();
  const int cnt_all = credi[0] + credi[1] + credi[2] + credi[3];
  float v = s / (float)cnt_all;
  float ss = v * v;
  #pragma unroll
  for (int o = 1; o < 64; o <<= 1) ss += __shfl_xor(ss, o);
  if ((d & 63) == 0) red[d >> 6] = ss;
  __syncthreads();
  float norm = sqrtf(red[0] + red[1] + red[2] + red[3]);
  cnorm[c * D_DIM + d] = v / fmaxf(norm, 1e-12f);
  if (d == 0) counts[c] = cnt_all;
}

// ---------- K3: pseudo-labels (fp32 argmax, class-pair ILP) + plain fp8 A cast ----------
__global__ void k_pseudo(const float* __restrict__ bf, const float* __restrict__ cn,
                         int* __restrict__ pseudo, u8* __restrict__ af8) {
  const int tid = threadIdx.x;
  const int rloc = tid >> 4, sub = tid & 15;
  const int row = blockIdx.x * 16 + rloc;
  float4 a[4];
  const float4* ap = (const float4*)(bf + (size_t)row * D_DIM);
  #pragma unroll
  for (int j = 0; j < 4; ++j) a[j] = ap[sub + j * 16];
  #pragma unroll
  for (int j = 0; j < 4; ++j) {
    int lo = __builtin_amdgcn_cvt_pk_fp8_f32(a[j].x * 16.f, a[j].y * 16.f, 0, false);
    int pk = __builtin_amdgcn_cvt_pk_fp8_f32(a[j].z * 16.f, a[j].w * 16.f, lo, true);
    *(unsigned int*)(af8 + (size_t)row * D_DIM + (sub + j * 16) * 4) = (unsigned int)pk;
  }
  float best = -1e30f; int bi = 0;
  for (int c = 0; c < C_CLS; c += 2) {
    const float4* cp0 = (const float4*)(cn + c * D_DIM);
    const float4* cp1 = (const float4*)(cn + (c + 1) * D_DIM);
    float s0 = 0.f, s1 = 0.f;
    #pragma unroll
    for (int j = 0; j < 4; ++j) {
      float4 b0 = cp0[sub + j * 16];
      float4 b1 = cp1[sub + j * 16];
      s0 += a[j].x * b0.x + a[j].y * b0.y + a[j].z * b0.z + a[j].w * b0.w;
      s1 += a[j].x * b1.x + a[j].y * b1.y + a[j].z * b1.z + a[j].w * b1.w;
    }
    s0 += __shfl_xor(s0, 1); s1 += __shfl_xor(s1, 1);
    s0 += __shfl_xor(s0, 2); s1 += __shfl_xor(s1, 2);
    s0 += __shfl_xor(s0, 4); s1 += __shfl_xor(s1, 4);
    s0 += __shfl_xor(s0, 8); s1 += __shfl_xor(s1, 8);
    if (s0 > best) { best = s0; bi = c; }
    if (s1 > best) { best = s1; bi = c + 1; }
  }
  if (sub == 0) pseudo[row] = bi;
}

// ---------- K5: MX-scaled fp8 MFMA GEMM (32x32x64, scales=1.0) + sqrt + masked sums ----------
// Identical to R13 except __launch_bounds__(512, 3): R13's (512,4) = 128-reg/wave
// hard cap < ~145 needed -> accumulator spill (FETCH 121MB, WRITE 39MB of scratch).
// (512,3) = 170-reg cap fits the working set; 3 waves/SIMD is enough overlap (R12).
__global__ __launch_bounds__(512, 3) void k_main(
    const u8* __restrict__ Af8, const u8* __restrict__ Qf8,
    const int* __restrict__ lab, const int* __restrict__ pseudo,
    float* __restrict__ S_all, float* __restrict__ S_match) {
  __shared__ u8 Bs[2][64 * 256];        // 2 x 16KB

  const int bid = blockIdx.x;
  const int xcd = bid & 7, idx = bid >> 3;
  const int cs = xcd * 4 + (idx >> 4);            // 0..31 col slice (1024 cols)
  const int rb = idx & 15;                        // 0..15 row block (256 rows)

  const int tid = threadIdx.x;
  const int w = tid >> 6, l = tid & 63;
  const int c32 = l & 31, hi32 = l >> 5;
  const int rowA = rb * 256 + w * 32;             // wave's 32 rows
  const int colbase = cs * 1024;

  // A-fragments: lane holds row rowA+c32, k = ks*64 + hi32*32 + [0,32). 32 regs.
  i32x4 areg[4][2];
  {
    const u8* ap = Af8 + (size_t)(rowA + c32) * D_DIM + hi32 * 32;
    #pragma unroll
    for (int ks = 0; ks < 4; ++ks) {
      areg[ks][0] = *(const i32x4*)(ap + ks * 64);
      areg[ks][1] = *(const i32x4*)(ap + ks * 64 + 16);
    }
  }

  // pseudo-labels, byte-packed: psepk[g] = rows rowA + 4*hi32 + 8*g + {0..3}
  int psepk[4];
  #pragma unroll
  for (int g = 0; g < 4; ++g) {
    const int* pp = pseudo + rowA + hi32 * 4 + g * 8;
    psepk[g] = pp[0] | (pp[1] << 8) | (pp[2] << 16) | (pp[3] << 24);
  }

  float pa[16], pm[16];
  #pragma unroll
  for (int r = 0; r < 16; ++r) { pa[r] = 0.f; pm[r] = 0.f; }

  // Staging: linear LDS dest (tid*16 + i*8192); source pre-swizzled with the
  // read involution: row = i*32 + (t>>4), slot = (t&15)<<4 ^ ((row&15)<<4).
  const int strow = tid >> 4;                     // 0..31
  const int sinner = (((tid & 15) ^ (strow & 15)) << 4);
  const u8* sbase = Qf8 + (size_t)(colbase + strow) * D_DIM + sinner;

#define STAGE(buf, ph)                                                    \
  { const u8* s_ = sbase + (size_t)(ph) * (64 * D_DIM);                   \
    GLDS16(s_,              (buf) + tid * 16);                            \
    GLDS16(s_ + 32 * D_DIM, (buf) + 8192 + tid * 16); }

  const int* lptr = lab + colbase + c32;
  const int xorm = (c32 & 15) << 4;               // read-side swizzle (row = n*32+c32)
  const unsigned int SC1 = 0x7F7F7F7Fu;           // E8M0 = 2^0 per 32-elem block

  STAGE(&Bs[0][0], 0);                            // prologue

  #pragma unroll 1
  for (int ph = 0; ph < 16; ++ph) {
    __syncthreads();                              // buf[ph&1] staged
    if (ph + 1 < 16) STAGE(&Bs[(ph + 1) & 1][0], ph + 1);
    const u8* bs = &Bs[ph & 1][0];
    const int lbl0 = lptr[ph * 64];
    const int lbl1 = lptr[ph * 64 + 32];

    f32x16 acc0{}, acc1{};
    #pragma unroll
    for (int ks = 0; ks < 4; ++ks) {
      const int off = ks * 64 + hi32 * 32;
      i32x4 b0l = *(const i32x4*)(bs + c32 * 256 + (off ^ xorm));
      i32x4 b0h = *(const i32x4*)(bs + c32 * 256 + ((off + 16) ^ xorm));
      i32x4 b1l = *(const i32x4*)(bs + (32 + c32) * 256 + (off ^ xorm));
      i32x4 b1h = *(const i32x4*)(bs + (32 + c32) * 256 + ((off + 16) ^ xorm));
      i32x8 av = mk8(areg[ks][0], areg[ks][1]);
      acc0 = __builtin_amdgcn_mfma_scale_f32_32x32x64_f8f6f4(
          av, mk8(b0l, b0h), acc0, 0, 0, 0, SC1, 0, SC1);
      acc1 = __builtin_amdgcn_mfma_scale_f32_32x32x64_f8f6f4(
          av, mk8(b1l, b1h), acc1, 0, 0, 0, SC1, 0, SC1);
    }

    // MAE epilogue: sim = acc/256 -> mae = sqrt(2 - acc/128 + 1e-6)
    #pragma unroll
    for (int r = 0; r < 16; ++r) {
      const int p = (psepk[r >> 2] >> ((r & 3) * 8)) & 255;
      float mae0 = fast_sqrt(fmaxf(__builtin_fmaf(-0.0078125f, acc0[r], 2.000001f), 0.0f));
      float mae1 = fast_sqrt(fmaxf(__builtin_fmaf(-0.0078125f, acc1[r], 2.000001f), 0.0f));
      pa[r] += mae0 + mae1;
      pm[r] += (lbl0 == p ? mae0 : 0.0f) + (lbl1 == p ? mae1 : 0.0f);
    }
  }

  // once per block: reduce over the 32 col-lanes, then atomics
  #pragma unroll
  for (int r = 0; r < 16; ++r) {
    float va = pa[r], vm = pm[r];
    va += __shfl_xor(va, 1); vm += __shfl_xor(vm, 1);
    va += __shfl_xor(va, 2); vm += __shfl_xor(vm, 2);
    va += __shfl_xor(va, 4); vm += __shfl_xor(vm, 4);
    va += __shfl_xor(va, 8); vm += __shfl_xor(vm, 8);
    va += __shfl_xor(va, 16); vm += __shfl_xor(vm, 16);
    if (c32 == 0) {
      const int gr = rowA + (r & 3) + 8 * (r >> 2) + 4 * hi32;
      atomicAdd(&S_all[gr], va);
      atomicAdd(&S_match[gr], vm);
    }
  }
#undef STAGE
}

// ---------- K6: final scalar ----------
__global__ void k_final(const float* __restrict__ S_all, const float* __restrict__ S_match,
                        const int* __restrict__ pseudo, const int* __restrict__ counts,
                        float* __restrict__ out) {
  __shared__ float r1[16], r2[16];
  const int tid = threadIdx.x;
  float s1 = 0.f, s2 = 0.f;
  for (int b = tid; b < B_ROWS; b += 1024) {
    float cnt = (float)counts[pseudo[b]];
    float sm = S_match[b], sa = S_all[b];
    s1 += sm / (cnt + 1e-6f);
    s2 += (sa - sm) / ((float)K_Q - cnt + 1e-6f);
  }
  #pragma unroll
  for (int o = 1; o < 64; o <<= 1) { s1 += __shfl_xor(s1, o); s2 += __shfl_xor(s2, o); }
  if ((tid & 63) == 0) { r1[tid >> 6] = s1; r2[tid >> 6] = s2; }
  __syncthreads();
  if (tid == 0) {
    float t1 = 0.f, t2 = 0.f;
    #pragma unroll
    for (int i = 0; i < 16; ++i) { t1 += r1[i]; t2 += r2[i]; }
    out[0] = t1 / (float)B_ROWS + 2.0f - t2 / (float)B_ROWS;
  }
}

extern "C" void kernel_launch(void* const* d_in, const int* in_sizes, int n_in,
                              void* d_out, int out_size, void* d_ws, size_t ws_size,
                              hipStream_t stream) {
  const float* batch = (const float*)d_in[0];
  const float* queue = (const float*)d_in[1];
  const int*   lab   = (const int*)d_in[2];

  char* ws = (char*)d_ws;
  float* S_all   = (float*)(ws + 0);             // 16KB (zeroed by k_hist)
  float* S_match = (float*)(ws + 16384);         // 16KB (zeroed by k_hist)
  int*   counts  = (int*)  (ws + 32768);         // 512B
  float* cnorm   = (float*)(ws + 33280);         // 100KB
  int*   pseudo  = (int*)  (ws + 135680);        // 16KB
  u8*    Af8     = (u8*)   (ws + 152064);        // 1MB
  u8*    Qf8     = (u8*)   (ws + 1200640);       // 8MB
  float* partial = (float*)(ws + 9589248);       // 6.5MB

  k_hist  <<<dim3(64, 4), 512, 0, stream>>>(queue, lab, partial, Qf8, S_all, S_match);
  k_cnorm <<<C_CLS, 256, 0, stream>>>(lab, partial, counts, cnorm);
  k_pseudo<<<B_ROWS / 16, 256, 0, stream>>>(batch, cnorm, pseudo, Af8);
  k_main  <<<512, 512, 0, stream>>>(Af8, Qf8, lab, pseudo, S_all, S_match);
  k_final <<<1, 1024, 0, stream>>>(S_all, S_match, pseudo, counts, (float*)d_out);
}

// Round 15
// 151.470 us; speedup vs baseline: 1.3551x; 1.0260x over previous
//
#include <hip/hip_runtime.h>

#define B_ROWS 4096
#define K_Q    32768
#define D_DIM  256
#define C_CLS  100

typedef unsigned char u8;
typedef __attribute__((ext_vector_type(4))) int i32x4;
typedef __attribute__((ext_vector_type(8))) int i32x8;
typedef __attribute__((ext_vector_type(16))) float f32x16;

__device__ inline float fast_sqrt(float x) { return __builtin_amdgcn_sqrtf(x); }

__device__ inline i32x8 mk8(i32x4 lo, i32x4 hi) {
  return __builtin_shufflevector(lo, hi, 0, 1, 2, 3, 4, 5, 6, 7);
}

#define GLDS16(g, l) __builtin_amdgcn_global_load_lds( \
    (const __attribute__((address_space(1))) unsigned int*)(g), \
    (__attribute__((address_space(3))) unsigned int*)(l), 16, 0, 0)

// fp8 storage: PLAIN k-major 256B/row (the 32x32x64 MFMA fragment is 32
// contiguous k-bytes per lane).

// ---------- K1: per-class partial sums + fused fp8 cast of Q + zero S ----------
__global__ __launch_bounds__(512) void k_hist(
    const float* __restrict__ q, const int* __restrict__ lab,
    float* __restrict__ partial, u8* __restrict__ qf8,
    float* __restrict__ S_all, float* __restrict__ S_match) {
  __shared__ float lsum[C_CLS * 64];    // 25.6 KB
  const int kc = blockIdx.x, dc = blockIdx.y;
  const int tid = threadIdx.x, w = tid >> 6, l = tid & 63;
  if (dc == 0 && tid < 64) {            // replaces the memset node
    S_all[kc * 64 + tid] = 0.f;
    S_match[kc * 64 + tid] = 0.f;
  }
  for (int i = tid; i < C_CLS * 64; i += 512) lsum[i] = 0.f;
  __syncthreads();
  const int col = dc * 64 + l;
  const int k0 = kc * 512 + w * 64;
  #pragma unroll 4
  for (int r = 0; r < 64; ++r) {
    const int k = k0 + r;
    const int c = lab[k];                         // wave-uniform
    float v = q[(size_t)k * D_DIM + col];
    atomicAdd(&lsum[c * 64 + l], v);              // ds_add_f32
    int p8 = __builtin_amdgcn_cvt_pk_fp8_f32(v * 16.f, v * 16.f, 0, false);
    qf8[(size_t)k * D_DIM + col] = (u8)p8;        // plain layout, 64B/wave coalesced
  }
  __syncthreads();
  float* pb = partial + (size_t)(kc * 4 + dc) * (C_CLS * 64);
  for (int i = tid; i < C_CLS * 64; i += 512) pb[i] = lsum[i];
}

// ---------- K2: counts (from lab) + partial-reduce + centroid normalize ----------
__global__ __launch_bounds__(256) void k_cnorm(
    const int* __restrict__ lab, const float* __restrict__ partial,
    int* __restrict__ counts, float* __restrict__ cnorm) {
  __shared__ float red[4];
  __shared__ int credi[4];
  const int c = blockIdx.x, d = threadIdx.x;
  int cnt = 0;
  #pragma unroll 8
  for (int i = 0; i < K_Q / 256; ++i) cnt += (lab[d + i * 256] == c) ? 1 : 0;
  #pragma unroll
  for (int o = 1; o < 64; o <<= 1) cnt += __shfl_xor(cnt, o);
  if ((d & 63) == 0) credi[d >> 6] = cnt;
  float s = 0.f;
  const int dcsel = d >> 6, low = d & 63;
  for (int kc = 0; kc < 64; ++kc)
    s += partial[(size_t)(kc * 4 + dcsel) * (C_CLS * 64) + c * 64 + low];
  __syncthreads();
  const int cnt_all = credi[0] + credi[1] + credi[2] + credi[3];
  float v = s / (float)cnt_all;
  float ss = v * v;
  #pragma unroll
  for (int o = 1; o < 64; o <<= 1) ss += __shfl_xor(ss, o);
  if ((d & 63) == 0) red[d >> 6] = ss;
  __syncthreads();
  float norm = sqrtf(red[0] + red[1] + red[2] + red[3]);
  cnorm[c * D_DIM + d] = v / fmaxf(norm, 1e-12f);
  if (d == 0) counts[c] = cnt_all;
}

// ---------- K3: pseudo-labels (fp32 argmax, class-pair ILP) + plain fp8 A cast ----------
__global__ void k_pseudo(const float* __restrict__ bf, const float* __restrict__ cn,
                         int* __restrict__ pseudo, u8* __restrict__ af8) {
  const int tid = threadIdx.x;
  const int rloc = tid >> 4, sub = tid & 15;
  const int row = blockIdx.x * 16 + rloc;
  float4 a[4];
  const float4* ap = (const float4*)(bf + (size_t)row * D_DIM);
  #pragma unroll
  for (int j = 0; j < 4; ++j) a[j] = ap[sub + j * 16];
  #pragma unroll
  for (int j = 0; j < 4; ++j) {
    int lo = __builtin_amdgcn_cvt_pk_fp8_f32(a[j].x * 16.f, a[j].y * 16.f, 0, false);
    int pk = __builtin_amdgcn_cvt_pk_fp8_f32(a[j].z * 16.f, a[j].w * 16.f, lo, true);
    *(unsigned int*)(af8 + (size_t)row * D_DIM + (sub + j * 16) * 4) = (unsigned int)pk;
  }
  float best = -1e30f; int bi = 0;
  for (int c = 0; c < C_CLS; c += 2) {
    const float4* cp0 = (const float4*)(cn + c * D_DIM);
    const float4* cp1 = (const float4*)(cn + (c + 1) * D_DIM);
    float s0 = 0.f, s1 = 0.f;
    #pragma unroll
    for (int j = 0; j < 4; ++j) {
      float4 b0 = cp0[sub + j * 16];
      float4 b1 = cp1[sub + j * 16];
      s0 += a[j].x * b0.x + a[j].y * b0.y + a[j].z * b0.z + a[j].w * b0.w;
      s1 += a[j].x * b1.x + a[j].y * b1.y + a[j].z * b1.z + a[j].w * b1.w;
    }
    s0 += __shfl_xor(s0, 1); s1 += __shfl_xor(s1, 1);
    s0 += __shfl_xor(s0, 2); s1 += __shfl_xor(s1, 2);
    s0 += __shfl_xor(s0, 4); s1 += __shfl_xor(s1, 4);
    s0 += __shfl_xor(s0, 8); s1 += __shfl_xor(s1, 8);
    if (s0 > best) { best = s0; bi = c; }
    if (s1 > best) { best = s1; bi = c + 1; }
  }
  if (sub == 0) pseudo[row] = bi;
}

// ---------- K5: MX-scaled fp8 MFMA GEMM (32x32x64, scales=1.0) + sqrt + masked sums ----------
// R15: 256-thread blocks (4 waves). R14's 512-thr block was an 8-wave occupancy
// quantum: 3-waves/SIMD budget -> only 1 block (8 waves, 20.7%) resident. 4-wave
// blocks pack 3 blocks/CU = 12 waves = 37.5%, overlapping the VALU epilogue
// (the dominant cost: ~7 VALU/elem x 134M elems) with MFMA/barrier phases.
__global__ __launch_bounds__(256, 3) void k_main(
    const u8* __restrict__ Af8, const u8* __restrict__ Qf8,
    const int* __restrict__ lab, const int* __restrict__ pseudo,
    float* __restrict__ S_all, float* __restrict__ S_match) {
  __shared__ u8 Bs[2][64 * 256];        // 2 x 16KB

  const int bid = blockIdx.x;           // 1024 blocks = 8 xcd x (4 cs x 32 rb)
  const int xcd = bid & 7, idx = bid >> 3;
  const int cs = xcd * 4 + (idx >> 5);            // 0..31 col slice (1024 cols)
  const int rb = idx & 31;                        // 0..31 row block (128 rows)

  const int tid = threadIdx.x;
  const int w = tid >> 6, l = tid & 63;
  const int c32 = l & 31, hi32 = l >> 5;
  const int rowA = rb * 128 + w * 32;             // wave's 32 rows
  const int colbase = cs * 1024;

  // A-fragments: lane holds row rowA+c32, k = ks*64 + hi32*32 + [0,32). 32 regs.
  i32x4 areg[4][2];
  {
    const u8* ap = Af8 + (size_t)(rowA + c32) * D_DIM + hi32 * 32;
    #pragma unroll
    for (int ks = 0; ks < 4; ++ks) {
      areg[ks][0] = *(const i32x4*)(ap + ks * 64);
      areg[ks][1] = *(const i32x4*)(ap + ks * 64 + 16);
    }
  }

  // pseudo-labels, byte-packed: psepk[g] = rows rowA + 4*hi32 + 8*g + {0..3}
  int psepk[4];
  #pragma unroll
  for (int g = 0; g < 4; ++g) {
    const int* pp = pseudo + rowA + hi32 * 4 + g * 8;
    psepk[g] = pp[0] | (pp[1] << 8) | (pp[2] << 16) | (pp[3] << 24);
  }

  float pa[16], pm[16];
  #pragma unroll
  for (int r = 0; r < 16; ++r) { pa[r] = 0.f; pm[r] = 0.f; }

  // Staging: linear LDS dest (i*4096 + tid*16); source pre-swizzled with the
  // read involution. Chunk j = i*256+tid: row = i*16 + (t>>4), slot = t&15;
  // swizzled slot = (t&15) ^ (row&15), row&15 = (t>>4)&15 (i*16 = 0 mod 16).
  const int strow = tid >> 4;                     // 0..15
  const int sinner = (((tid & 15) ^ strow) << 4);
  const u8* sbase = Qf8 + (size_t)(colbase + strow) * D_DIM + sinner;

#define STAGE(buf, ph)                                                    \
  { const u8* s_ = sbase + (size_t)(ph) * (64 * D_DIM);                   \
    _Pragma("unroll")                                                     \
    for (int i_ = 0; i_ < 4; ++i_)                                        \
      GLDS16(s_ + (size_t)i_ * (16 * D_DIM), (buf) + i_ * 4096 + tid * 16); }

  const int* lptr = lab + colbase + c32;
  const int xorm = (c32 & 15) << 4;               // read-side swizzle (row = n*32+c32)
  const unsigned int SC1 = 0x7F7F7F7Fu;           // E8M0 = 2^0 per 32-elem block

  STAGE(&Bs[0][0], 0);                            // prologue

  #pragma unroll 1
  for (int ph = 0; ph < 16; ++ph) {
    __syncthreads();                              // buf[ph&1] staged
    if (ph + 1 < 16) STAGE(&Bs[(ph + 1) & 1][0], ph + 1);
    const u8* bs = &Bs[ph & 1][0];
    const int lbl0 = lptr[ph * 64];
    const int lbl1 = lptr[ph * 64 + 32];

    f32x16 acc0{}, acc1{};
    #pragma unroll
    for (int ks = 0; ks < 4; ++ks) {
      const int off = ks * 64 + hi32 * 32;
      i32x4 b0l = *(const i32x4*)(bs + c32 * 256 + (off ^ xorm));
      i32x4 b0h = *(const i32x4*)(bs + c32 * 256 + ((off + 16) ^ xorm));
      i32x4 b1l = *(const i32x4*)(bs + (32 + c32) * 256 + (off ^ xorm));
      i32x4 b1h = *(const i32x4*)(bs + (32 + c32) * 256 + ((off + 16) ^ xorm));
      i32x8 av = mk8(areg[ks][0], areg[ks][1]);
      acc0 = __builtin_amdgcn_mfma_scale_f32_32x32x64_f8f6f4(
          av, mk8(b0l, b0h), acc0, 0, 0, 0, SC1, 0, SC1);
      acc1 = __builtin_amdgcn_mfma_scale_f32_32x32x64_f8f6f4(
          av, mk8(b1l, b1h), acc1, 0, 0, 0, SC1, 0, SC1);
    }

    // MAE epilogue: sim = acc/256 -> mae = sqrt(2 - acc/128 + 1e-6)
    #pragma unroll
    for (int r = 0; r < 16; ++r) {
      const int p = (psepk[r >> 2] >> ((r & 3) * 8)) & 255;
      float mae0 = fast_sqrt(fmaxf(__builtin_fmaf(-0.0078125f, acc0[r], 2.000001f), 0.0f));
      float mae1 = fast_sqrt(fmaxf(__builtin_fmaf(-0.0078125f, acc1[r], 2.000001f), 0.0f));
      pa[r] += mae0 + mae1;
      pm[r] += (lbl0 == p ? mae0 : 0.0f) + (lbl1 == p ? mae1 : 0.0f);
    }
  }

  // once per block: reduce over the 32 col-lanes, then atomics
  #pragma unroll
  for (int r = 0; r < 16; ++r) {
    float va = pa[r], vm = pm[r];
    va += __shfl_xor(va, 1); vm += __shfl_xor(vm, 1);
    va += __shfl_xor(va, 2); vm += __shfl_xor(vm, 2);
    va += __shfl_xor(va, 4); vm += __shfl_xor(vm, 4);
    va += __shfl_xor(va, 8); vm += __shfl_xor(vm, 8);
    va += __shfl_xor(va, 16); vm += __shfl_xor(vm, 16);
    if (c32 == 0) {
      const int gr = rowA + (r & 3) + 8 * (r >> 2) + 4 * hi32;
      atomicAdd(&S_all[gr], va);
      atomicAdd(&S_match[gr], vm);
    }
  }
#undef STAGE
}

// ---------- K6: final scalar ----------
__global__ void k_final(const float* __restrict__ S_all, const float* __restrict__ S_match,
                        const int* __restrict__ pseudo, const int* __restrict__ counts,
                        float* __restrict__ out) {
  __shared__ float r1[16], r2[16];
  const int tid = threadIdx.x;
  float s1 = 0.f, s2 = 0.f;
  for (int b = tid; b < B_ROWS; b += 1024) {
    float cnt = (float)counts[pseudo[b]];
    float sm = S_match[b], sa = S_all[b];
    s1 += sm / (cnt + 1e-6f);
    s2 += (sa - sm) / ((float)K_Q - cnt + 1e-6f);
  }
  #pragma unroll
  for (int o = 1; o < 64; o <<= 1) { s1 += __shfl_xor(s1, o); s2 += __shfl_xor(s2, o); }
  if ((tid & 63) == 0) { r1[tid >> 6] = s1; r2[tid >> 6] = s2; }
  __syncthreads();
  if (tid == 0) {
    float t1 = 0.f, t2 = 0.f;
    #pragma unroll
    for (int i = 0; i < 16; ++i) { t1 += r1[i]; t2 += r2[i]; }
    out[0] = t1 / (float)B_ROWS + 2.0f - t2 / (float)B_ROWS;
  }
}

extern "C" void kernel_launch(void* const* d_in, const int* in_sizes, int n_in,
                              void* d_out, int out_size, void* d_ws, size_t ws_size,
                              hipStream_t stream) {
  const float* batch = (const float*)d_in[0];
  const float* queue = (const float*)d_in[1];
  const int*   lab   = (const int*)d_in[2];

  char* ws = (char*)d_ws;
  float* S_all   = (float*)(ws + 0);             // 16KB (zeroed by k_hist)
  float* S_match = (float*)(ws + 16384);         // 16KB (zeroed by k_hist)
  int*   counts  = (int*)  (ws + 32768);         // 512B
  float* cnorm   = (float*)(ws + 33280);         // 100KB
  int*   pseudo  = (int*)  (ws + 135680);        // 16KB
  u8*    Af8     = (u8*)   (ws + 152064);        // 1MB
  u8*    Qf8     = (u8*)   (ws + 1200640);       // 8MB
  float* partial = (float*)(ws + 9589248);       // 6.5MB

  k_hist  <<<dim3(64, 4), 512, 0, stream>>>(queue, lab, partial, Qf8, S_all, S_match);
  k_cnorm <<<C_CLS, 256, 0, stream>>>(lab, partial, counts, cnorm);
  k_pseudo<<<B_ROWS / 16, 256, 0, stream>>>(batch, cnorm, pseudo, Af8);
  k_main  <<<1024, 256, 0, stream>>>(Af8, Qf8, lab, pseudo, S_all, S_match);
  k_final <<<1, 1024, 0, stream>>>(S_all, S_match, pseudo, counts, (float*)d_out);
}